// Round 3
// baseline (4692.476 us; speedup 1.0000x reference)
//
#include <hip/hip_runtime.h>
#include <math.h>

#define XSS 68   // xtile row stride (floats): 272B rows, 16B-aligned, spreads staging-write banks
#define OS  68   // otile row stride

__device__ __forceinline__ float rcp_(float x) { return __builtin_amdgcn_rcpf(x); }
__device__ __forceinline__ float sigm(float v) { return rcp_(1.0f + __expf(-v)); }
__device__ __forceinline__ float tanh_(float v) {
    float av = fabsf(v);
    float e  = __expf(-2.0f * av);
    float r  = (1.0f - e) * rcp_(1.0f + e);
    return copysignf(r, v);
}
__device__ __forceinline__ float hsum(float4 a) { return (a.x + a.y) + (a.z + a.w); }

// Unit-major 2-layer LSTM. 128 blocks (1 per batch), 256 threads = 4 waves:
//   wave0: pA = Wih0 . x_t        (+ staging/flush chores)
//   wave1: pB = Whh0 . h0[n-1]    -> redundant L0 update, own h0 slot
//   wave2: pC = Wih1 . h0[n-1]    -> redundant L0 update, own h0 slot
//   wave3: pD = Whh1 . h1[n-2]    -> L1 update, own h1 slot, output
// Lane u owns unit u (4 gate rows u, u+64, u+128, u+192 in VGPRs).
// ONE __syncthreads per step (between partial-writes and partial-reads).
__global__ __launch_bounds__(256, 1) void lstm2_um(
    const float* __restrict__ x,
    const float* __restrict__ wih0, const float* __restrict__ whh0,
    const float* __restrict__ b0,
    const float* __restrict__ wih1, const float* __restrict__ whh1,
    const float* __restrict__ b1,
    float* __restrict__ out)
{
    const int b   = blockIdx.x;
    const int tid = threadIdx.x;
    const int wv  = tid >> 6;
    const int u   = tid & 63;

    __shared__ float xt[2][64 * XSS];           // xt[buf][tl*XSS + c]
    __shared__ float ot[2][64 * OS];            // ot[buf][h*OS + tl]
    __shared__ __align__(16) float h0w1[64], h0w2[64], h1w3[64];
    __shared__ float4 pA[2][64], pB[2][64], pC[2][64], pD[2][64];

    const float* Wm = (wv == 0) ? wih0 : (wv == 1) ? whh0 : (wv == 2) ? wih1 : whh1;

    // 4 gate rows x 64 weights, resident in VGPRs (256 regs)
    float4 wgt[4][16];
#pragma unroll
    for (int g = 0; g < 4; ++g) {
        const float4* rp = (const float4*)(Wm + (size_t)(u + 64 * g) * 64);
#pragma unroll
        for (int k = 0; k < 16; ++k) wgt[g][k] = rp[k];
    }

    float4 bia = make_float4(0.f, 0.f, 0.f, 0.f);
    if (wv == 1 || wv == 2) bia = make_float4(b0[u], b0[u + 64], b0[u + 128], b0[u + 192]);
    else if (wv == 3)       bia = make_float4(b1[u], b1[u + 64], b1[u + 128], b1[u + 192]);

    if (wv == 1) h0w1[u] = 0.f;
    if (wv == 2) h0w2[u] = 0.f;
    if (wv == 3) h1w3[u] = 0.f;

    const float* xb = x   + (size_t)b * 64 * 4096;
    float*       ob = out + (size_t)b * 64 * 4096;

    // stage x tile 0 with all threads
    for (int idx = tid; idx < 64 * 16; idx += 256) {
        int c = idx >> 4, q = idx & 15;
        float4 v = *(const float4*)(xb + (size_t)c * 4096 + 4 * q);
        xt[0][(4 * q + 0) * XSS + c] = v.x;
        xt[0][(4 * q + 1) * XSS + c] = v.y;
        xt[0][(4 * q + 2) * XSS + c] = v.z;
        xt[0][(4 * q + 3) * XSS + c] = v.w;
    }
    __syncthreads();

    float cst = 0.f;  // c0 in waves 1,2 ; c1 in wave 3

    const float* opbase = (wv == 2) ? h0w2 : (wv == 3) ? h1w3 : h0w1;

    for (int n = 0; n <= 4096; ++n) {
        const int buf = n & 1;

        // ---- dot phase: 4 gates x K=64, operand broadcast from LDS ----
        {
            const float4* op;
            bool active = true;
            if (wv == 0) {
                active = (n < 4096);
                op = (const float4*)(xt[(n >> 6) & 1] + (n & 63) * XSS);
            } else {
                op = (const float4*)opbase;
            }
            if (active) {
                float ax[4], ay[4], az[4], aw[4];
#pragma unroll
                for (int g = 0; g < 4; ++g) { ax[g] = 0.f; ay[g] = 0.f; az[g] = 0.f; aw[g] = 0.f; }
#pragma unroll
                for (int k = 0; k < 16; ++k) {
                    float4 v = op[k];
#pragma unroll
                    for (int g = 0; g < 4; ++g) {
                        ax[g] += wgt[g][k].x * v.x;
                        ay[g] += wgt[g][k].y * v.y;
                        az[g] += wgt[g][k].z * v.z;
                        aw[g] += wgt[g][k].w * v.w;
                    }
                }
                float4 P = make_float4(
                    (ax[0] + ay[0]) + (az[0] + aw[0]),
                    (ax[1] + ay[1]) + (az[1] + aw[1]),
                    (ax[2] + ay[2]) + (az[2] + aw[2]),
                    (ax[3] + ay[3]) + (az[3] + aw[3]));
                if      (wv == 0) pA[buf][u] = P;
                else if (wv == 1) pB[buf][u] = P;
                else if (wv == 2) pC[buf][u] = P;
                else              pD[buf][u] = P;
            }
        }
        __syncthreads();

        // ---- update phase ----
        if ((wv == 1 || wv == 2) && n < 4096) {
            float4 qa = pA[buf][u], qb = pB[buf][u];
            float pi_ = qa.x + qb.x + bia.x;
            float pf_ = qa.y + qb.y + bia.y;
            float pg_ = qa.z + qb.z + bia.z;
            float po_ = qa.w + qb.w + bia.w;
            float ii = sigm(pi_), ff = sigm(pf_), gg = tanh_(pg_), oo = sigm(po_);
            cst = ff * cst + ii * gg;
            float h = oo * tanh_(cst);
            if (wv == 1) h0w1[u] = h; else h0w2[u] = h;
        } else if (wv == 3 && n >= 1) {
            float4 qc = pC[buf][u], qd = pD[buf][u];
            float pi_ = qc.x + qd.x + bia.x;
            float pf_ = qc.y + qd.y + bia.y;
            float pg_ = qc.z + qd.z + bia.z;
            float po_ = qc.w + qd.w + bia.w;
            float ii = sigm(pi_), ff = sigm(pf_), gg = tanh_(pg_), oo = sigm(po_);
            cst = ff * cst + ii * gg;
            float h = oo * tanh_(cst);
            h1w3[u] = h;
            ot[((n - 1) >> 6) & 1][u * OS + ((n - 1) & 63)] = h;
        } else if (wv == 0) {
            // chores in wave0's idle window
            if ((n & 63) == 32 && (n >> 6) < 63) {
                // stage x tile T=(n>>6)+1 into xt[T&1]
                int T = (n >> 6) + 1;
                int t0 = T * 64;
                float* dst = xt[T & 1];
                int q = u & 15;
#pragma unroll 1
                for (int i = 0; i < 16; ++i) {
                    int c = 4 * i + (u >> 4);
                    float4 v = *(const float4*)(xb + (size_t)c * 4096 + t0 + 4 * q);
                    dst[(4 * q + 0) * XSS + c] = v.x;
                    dst[(4 * q + 1) * XSS + c] = v.y;
                    dst[(4 * q + 2) * XSS + c] = v.z;
                    dst[(4 * q + 3) * XSS + c] = v.w;
                }
            } else if ((n & 63) == 1 && n > 64) {
                // flush output tile k=(n>>6)-1 from ot[k&1]
                int k  = (n >> 6) - 1;
                int t0 = k * 64;
                const float* src = ot[k & 1];
                int q = u & 15;
#pragma unroll 1
                for (int i = 0; i < 16; ++i) {
                    int r = 4 * i + (u >> 4);
                    float4 v = *(const float4*)(src + r * OS + 4 * q);
                    *(float4*)(ob + (size_t)r * 4096 + t0 + 4 * q) = v;
                }
            }
        }
        // single barrier per step: next iteration's dot reads only own-wave
        // LDS slots (h slots / xt) or double-buffered partials.
    }

    __syncthreads();
    // flush last tile (k=63, buf 1) with all threads
    for (int idx = tid; idx < 64 * 16; idx += 256) {
        int r = idx >> 4, q = idx & 15;
        float4 v = *(const float4*)(ot[1] + r * OS + 4 * q);
        *(float4*)(ob + (size_t)r * 4096 + 63 * 64 + 4 * q) = v;
    }
}

extern "C" void kernel_launch(void* const* d_in, const int* in_sizes, int n_in,
                              void* d_out, int out_size, void* d_ws, size_t ws_size,
                              hipStream_t stream) {
    const float* x    = (const float*)d_in[0];
    const float* wih0 = (const float*)d_in[1];
    const float* whh0 = (const float*)d_in[2];
    const float* b0   = (const float*)d_in[3];
    const float* wih1 = (const float*)d_in[4];
    const float* whh1 = (const float*)d_in[5];
    const float* b1   = (const float*)d_in[6];
    float* out = (float*)d_out;

    lstm2_um<<<128, 256, 0, stream>>>(x, wih0, whh0, b0, wih1, whh1, b1, out);
}

// Round 4
// 4357.823 us; speedup vs baseline: 1.0768x; 1.0768x over previous
//
#include <hip/hip_runtime.h>
#include <math.h>

#define TT 64      // timesteps per x/out tile staged in LDS
#define XS 68      // padded LDS row stride (floats)

// Opaque pin: forces the 4 components into VGPRs; compiler cannot remat
// asm outputs from global memory, so weights stay register-resident.
#define PIN4(v) asm volatile("" : "+v"(v.x), "+v"(v.y), "+v"(v.z), "+v"(v.w))

__device__ __forceinline__ float rcp_(float x) { return __builtin_amdgcn_rcpf(x); }
__device__ __forceinline__ float sigm(float v) { return rcp_(1.0f + __expf(-v)); }
__device__ __forceinline__ float tanh_(float v) {
    float av = fabsf(v);
    float e  = __expf(-2.0f * av);
    float r  = (1.0f - e) * rcp_(1.0f + e);
    return copysignf(r, v);
}

// One block per batch element. 512 threads:
//   tid 0..255   = layer 0, gate j = tid
//   tid 256..511 = layer 1, gate j = tid-256
// Layers SKEWED: at iteration n, layer0 does timestep n, layer1 does n-1.
// 2 barriers per iteration. h vectors double-buffered in LDS.
// Weights: 128 floats per thread, pinned into VGPRs (the R1/R2 designs
// silently rematerialized these from L1 every step — VGPR_Count showed it).
__global__ __launch_bounds__(512, 2) void lstm2_skew_pin(
    const float* __restrict__ x,      // [128][64][4096]
    const float* __restrict__ wih0,   // [256][64]
    const float* __restrict__ whh0,   // [256][64]
    const float* __restrict__ b0,     // [256]
    const float* __restrict__ wih1,   // [256][64]
    const float* __restrict__ whh1,   // [256][64]
    const float* __restrict__ b1,     // [256]
    float* __restrict__ out)          // [128][64][4096]
{
    const int b   = blockIdx.x;
    const int tid = threadIdx.x;
    const int layer = tid >> 8;       // wave-uniform (waves 0-3 = L0, 4-7 = L1)
    const int j   = tid & 255;

    __shared__ float xt[TT * XS];     // xt[tl][c] transposed x tile
    __shared__ float ot[64 * XS];     // ot[h][tl] output staging
    __shared__ float h0buf[2][64];
    __shared__ float h1buf[2][64];
    __shared__ float g0[256];
    __shared__ float g1[256];

    // Per-thread weights: one gate row of one layer (128 floats = 32 float4).
    float4 wx[16], wh[16];
    {
        const float* wxp = (layer == 0 ? wih0 : wih1) + j * 64;
        const float* whp = (layer == 0 ? whh0 : whh1) + j * 64;
#pragma unroll
        for (int i = 0; i < 16; ++i) wx[i] = ((const float4*)wxp)[i];
#pragma unroll
        for (int i = 0; i < 16; ++i) wh[i] = ((const float4*)whp)[i];
#pragma unroll
        for (int i = 0; i < 16; ++i) { PIN4(wx[i]); PIN4(wh[i]); }
    }
    const float bias = (layer == 0 ? b0 : b1)[j];
    const bool tanh_gate = (j >= 128) && (j < 192);  // wave-uniform

    float cst = 0.0f;   // cell state: tid<64 holds c0, tid 256..319 holds c1

    if (tid < 64) {
        h0buf[0][tid] = 0.f; h0buf[1][tid] = 0.f;
        h1buf[0][tid] = 0.f; h1buf[1][tid] = 0.f;
    }

    const float* xb = x   + (size_t)b * 64 * 4096;
    float*       ob = out + (size_t)b * 64 * 4096;

    for (int n = 0; n <= 4096; ++n) {
        // ---- stage next x tile (every 64 iters); barrier covers h-init at n=0 ----
        if ((n & 63) == 0 && n < 4096) {
            for (int idx = tid; idx < 64 * 16; idx += 512) {
                int c = idx >> 4;      // channel
                int q = idx & 15;      // float4 index along t
                float4 v = *(const float4*)(xb + (size_t)c * 4096 + n + 4 * q);
                xt[(4 * q + 0) * XS + c] = v.x;
                xt[(4 * q + 1) * XS + c] = v.y;
                xt[(4 * q + 2) * XS + c] = v.z;
                xt[(4 * q + 3) * XS + c] = v.w;
            }
            __syncthreads();
        }

        // ---- phase A: both layers' gate GEMVs concurrently ----
        if (layer == 0) {
            if (n < 4096) {
                const float4* av = (const float4*)(xt + (n & 63) * XS);
                const float4* hv = (const float4*)(h0buf[n & 1]);
                float a0=0,a1=0,a2=0,a3=0,b0_=0,b1_=0,b2_=0,b3_=0;
#pragma unroll
                for (int i = 0; i < 16; ++i) {
                    float4 v = av[i];
                    a0 += wx[i].x * v.x; a1 += wx[i].y * v.y;
                    a2 += wx[i].z * v.z; a3 += wx[i].w * v.w;
                }
#pragma unroll
                for (int i = 0; i < 16; ++i) {
                    float4 v = hv[i];
                    b0_ += wh[i].x * v.x; b1_ += wh[i].y * v.y;
                    b2_ += wh[i].z * v.z; b3_ += wh[i].w * v.w;
                }
                float acc = ((a0 + a1) + (a2 + a3)) + ((b0_ + b1_) + (b2_ + b3_)) + bias;
                g0[j] = tanh_gate ? tanh_(acc) : sigm(acc);
            }
        } else {
            if (n >= 1) {
                const float4* av = (const float4*)(h0buf[n & 1]);   // input = h0[n-1]
                const float4* hv = (const float4*)(h1buf[n & 1]);   // recurrent h1[n-2]
                float a0=0,a1=0,a2=0,a3=0,b0_=0,b1_=0,b2_=0,b3_=0;
#pragma unroll
                for (int i = 0; i < 16; ++i) {
                    float4 v = av[i];
                    a0 += wx[i].x * v.x; a1 += wx[i].y * v.y;
                    a2 += wx[i].z * v.z; a3 += wx[i].w * v.w;
                }
#pragma unroll
                for (int i = 0; i < 16; ++i) {
                    float4 v = hv[i];
                    b0_ += wh[i].x * v.x; b1_ += wh[i].y * v.y;
                    b2_ += wh[i].z * v.z; b3_ += wh[i].w * v.w;
                }
                float acc = ((a0 + a1) + (a2 + a3)) + ((b0_ + b1_) + (b2_ + b3_)) + bias;
                g1[j] = tanh_gate ? tanh_(acc) : sigm(acc);
            }
        }
        __syncthreads();

        // ---- phase B: cell/hidden updates, both layers in parallel waves ----
        if (tid < 64) {                       // layer 0 update (wave 0)
            if (n < 4096) {
                float i_ = g0[tid];
                float f_ = g0[tid + 64];
                float gg = g0[tid + 128];
                float o_ = g0[tid + 192];
                cst = f_ * cst + i_ * gg;
                h0buf[(n + 1) & 1][tid] = o_ * tanh_(cst);
            }
        } else if (tid >= 256 && tid < 320) { // layer 1 update (wave 4)
            if (n >= 1) {
                int k = tid - 256;
                float i_ = g1[k];
                float f_ = g1[k + 64];
                float gg = g1[k + 128];
                float o_ = g1[k + 192];
                cst = f_ * cst + i_ * gg;
                float h = o_ * tanh_(cst);
                h1buf[(n + 1) & 1][k] = h;
                ot[k * XS + ((n - 1) & 63)] = h;
            }
        }
        __syncthreads();

        // ---- flush output tile every 64 iters (t1 range [n-64, n-1]) ----
        if (n > 0 && (n & 63) == 0) {
            int t0f = n - 64;
            for (int idx = tid; idx < 64 * 16; idx += 512) {
                int r = idx >> 4;
                int q = idx & 15;
                float4 v = *(const float4*)(ot + r * XS + 4 * q);
                *(float4*)(ob + (size_t)r * 4096 + t0f + 4 * q) = v;
            }
            // next write to ot happens after next iter's barriers
        }
    }
}

extern "C" void kernel_launch(void* const* d_in, const int* in_sizes, int n_in,
                              void* d_out, int out_size, void* d_ws, size_t ws_size,
                              hipStream_t stream) {
    const float* x    = (const float*)d_in[0];
    const float* wih0 = (const float*)d_in[1];
    const float* whh0 = (const float*)d_in[2];
    const float* b0   = (const float*)d_in[3];
    const float* wih1 = (const float*)d_in[4];
    const float* whh1 = (const float*)d_in[5];
    const float* b1   = (const float*)d_in[6];
    float* out = (float*)d_out;

    lstm2_skew_pin<<<128, 512, 0, stream>>>(x, wih0, whh0, b0, wih1, whh1, b1, out);
}